// Round 7
// baseline (905.384 us; speedup 1.0000x reference)
//
#include <hip/hip_runtime.h>
#include <hip/hip_cooperative_groups.h>

namespace cg = cooperative_groups;

#define N_NODES 50000
#define N_EDGES 600000
#define F 128
#define NTILES 782            // ceil(50000/64)
#define NBINS  (NTILES * 8)   // (dstTile, rel) bins = 6256
#define MAXGRID 512

// ---------- ws layout (16-aligned) ----------
#define WT_OFF   0            // 294,912 B   bf16 W [r][o][i], r=8 is loop_weight
#define H2_OFF   294912       // 12,800,000  bf16 h
#define GATE_OFF 13094912     // 1,600,000   sigmoid gates [r][n]
#define CNT_OFF  14694912     // 25,088      (dstTile,rel) histogram
#define BASE_OFF 14720000     // 25,088      exclusive scan (+sentinel)
#define CUR_OFF  14745088     // 25,088      scatter cursor
#define REC_OFF  14770176     // 4,800,000   {src | row6<<16, scale} per edge, bin-sorted
#define WS_NEED  ((size_t)19570176)

#define LDB 136               // sB short stride
#define LDF 132               // fAcc float stride (4-way max bank aliasing)

typedef __attribute__((ext_vector_type(8))) short short8;
typedef __attribute__((ext_vector_type(4))) float floatx4;

__device__ inline unsigned short f32_to_bf16(float f) {
    unsigned u = __float_as_uint(f);
    unsigned r = u + 0x7fff + ((u >> 16) & 1);
    return (unsigned short)(r >> 16);
}
__device__ inline float bf16lo(unsigned m) { return __uint_as_float(m << 16); }
__device__ inline float bf16hi(unsigned m) { return __uint_as_float(m & 0xffff0000u); }
__device__ inline float sigmoidf(float x) { return 1.f / (1.f + __expf(-x)); }

__device__ inline short8 pack_bf16x8(float4 a, float4 b) {
    short8 r;
    r[0] = (short)f32_to_bf16(a.x); r[1] = (short)f32_to_bf16(a.y);
    r[2] = (short)f32_to_bf16(a.z); r[3] = (short)f32_to_bf16(a.w);
    r[4] = (short)f32_to_bf16(b.x); r[5] = (short)f32_to_bf16(b.y);
    r[6] = (short)f32_to_bf16(b.z); r[7] = (short)f32_to_bf16(b.w);
    return r;
}

// ================== the single cooperative mega-kernel ==================
__global__ __launch_bounds__(1024, 8) void k_mega(
        const float* __restrict__ h,    const float* __restrict__ gw,
        const float* __restrict__ W,    const float* __restrict__ LW,
        const float* __restrict__ norm, const int* __restrict__ src,
        const int* __restrict__ dst,    const int* __restrict__ rel,
        const float* __restrict__ bias, float* __restrict__ out,
        unsigned short* __restrict__ h2, float* __restrict__ gate,
        unsigned short* __restrict__ Wt, int* __restrict__ cnt,
        int* __restrict__ base, int* __restrict__ cur, int2* __restrict__ rec) {
    cg::grid_group grid = cg::this_grid();
    __shared__ float fAcc[64 * LDF];            // 33,792 B fp32 accumulator tile
    __shared__ unsigned short sB[128 * LDB];    // 34,816 B bf16 W_kb

    int tid = threadIdx.x;
    int w = tid >> 6, lane = tid & 63;
    int gtid = blockIdx.x * 1024 + tid;
    int nthreads = gridDim.x << 10;
    int gwid = blockIdx.x * 16 + w;
    int nwaves = gridDim.x << 4;

    // ---- P0: zero histogram ----
    for (int i = gtid; i < NBINS; i += nthreads) cnt[i] = 0;
    grid.sync();

    // ---- P1: Wt prep, h->bf16, gates, histogram ----
    for (int i = gtid; i < 9 * 128 * 128; i += nthreads) {
        int r = i >> 14, rem = i & 16383, ii = rem >> 7, o = rem & 127;
        float v = (r < 8) ? W[(r << 14) + (ii << 7) + o] : LW[(ii << 7) + o];
        Wt[(r << 14) + (o << 7) + ii] = f32_to_bf16(v);
    }
    for (int n = gwid; n < N_NODES; n += nwaves) {
        float2 hv = *(const float2*)(h + (size_t)n * F + lane * 2);
        unsigned val = (unsigned)f32_to_bf16(hv.x) | ((unsigned)f32_to_bf16(hv.y) << 16);
        *(unsigned*)(h2 + (size_t)n * F + lane * 2) = val;
        #pragma unroll
        for (int r = 0; r < 8; ++r) {
            float2 wv = *(const float2*)(gw + r * F + lane * 2);
            float p = hv.x * wv.x + hv.y * wv.y;
            #pragma unroll
            for (int off = 32; off; off >>= 1) p += __shfl_xor(p, off);
            if (lane == 0) gate[r * N_NODES + n] = sigmoidf(p);
        }
    }
    for (int e = gtid; e < N_EDGES; e += nthreads)
        atomicAdd(&cnt[(dst[e] >> 6) * 8 + rel[e]], 1);
    grid.sync();

    // ---- P2: exclusive scan of 6256 bins (block 0 only) ----
    if (blockIdx.x == 0) {
        int* wsum = (int*)fAcc;
        const int CH = 7;                       // 1024*7 = 7168 >= 6256
        int st = tid * CH;
        int s = 0;
        #pragma unroll
        for (int i = 0; i < CH; ++i) {
            int idx = st + i;
            if (idx < NBINS) s += cnt[idx];
        }
        int x = s;
        #pragma unroll
        for (int off = 1; off < 64; off <<= 1) {
            int t = __shfl_up(x, off);
            if (lane >= off) x += t;
        }
        if (lane == 63) wsum[w] = x;
        __syncthreads();
        if (w == 0) {
            int y = (lane < 16) ? wsum[lane] : 0;
            #pragma unroll
            for (int off = 1; off < 16; off <<= 1) {
                int t = __shfl_up(y, off);
                if (lane >= off) y += t;
            }
            if (lane < 16) wsum[lane] = y;
        }
        __syncthreads();
        int pre = (w > 0) ? wsum[w - 1] : 0;
        int run = pre + x - s;
        #pragma unroll
        for (int i = 0; i < CH; ++i) {
            int idx = st + i;
            if (idx < NBINS) {
                int v = cnt[idx];
                base[idx] = run;
                cur[idx] = run;
                run += v;
            }
        }
        if (tid == 0) base[NBINS] = N_EDGES;
    }
    grid.sync();

    // ---- P3: scatter into bin-sorted rec ----
    for (int e = gtid; e < N_EDGES; e += nthreads) {
        int d = dst[e], r = rel[e], s = src[e];
        int pos = atomicAdd(&cur[(d >> 6) * 8 + r], 1);
        float sc = norm[e] * gate[r * N_NODES + s];
        rec[pos] = make_int2(s | ((d & 63) << 16), __float_as_int(sc));
    }
    grid.sync();

    // ---- P4: per-tile edge-parallel aggregate (LDS fp32 atomics) + MFMA ----
    int lrow = lane & 15, quad = lane >> 4;
    int mblk = w >> 2, nblk = w & 3;
    int fgrp = lane & 15, esub = lane >> 4;     // 16 lanes/edge, 4 edges/wave

    for (int tile = blockIdx.x; tile < NTILES; tile += gridDim.x) {
        int nb = tile * 64;
        floatx4 acc[2];
        acc[0] = (floatx4){0.f, 0.f, 0.f, 0.f};
        acc[1] = (floatx4){0.f, 0.f, 0.f, 0.f};

        for (int kb = 0; kb < 9; ++kb) {
            __syncthreads();                    // prior kb's LDS reads complete
            // stage W_kb
            #pragma unroll
            for (int it = 0; it < 2; ++it) {
                int G = it * 1024 + tid;
                int row = G >> 4, gr = G & 15;
                *(uint4*)(&sB[row * LDB + gr * 8]) = *(const uint4*)(Wt + (kb << 14) + G * 8);
            }
            if (kb < 8) {
                for (int z = tid; z < 64 * LDF; z += 1024) fAcc[z] = 0.f;
                __syncthreads();
                int bin = tile * 8 + kb;
                int s0 = base[bin], e0 = base[bin + 1];
                for (int j = s0 + w * 4; j < e0; j += 64) {
                    int eIdx = j + esub;
                    if (eIdx < e0) {
                        int2 rc = rec[eIdx];
                        float sc = __int_as_float(rc.y);
                        int sn = rc.x & 0xffff;
                        int row = (rc.x >> 16) & 63;
                        uint4 hv = *(const uint4*)(h2 + (size_t)sn * F + fgrp * 8);
                        float* fp = &fAcc[row * LDF + fgrp * 8];
                        unsafeAtomicAdd(fp + 0, sc * bf16lo(hv.x));
                        unsafeAtomicAdd(fp + 1, sc * bf16hi(hv.x));
                        unsafeAtomicAdd(fp + 2, sc * bf16lo(hv.y));
                        unsafeAtomicAdd(fp + 3, sc * bf16hi(hv.y));
                        unsafeAtomicAdd(fp + 4, sc * bf16lo(hv.z));
                        unsafeAtomicAdd(fp + 5, sc * bf16hi(hv.z));
                        unsafeAtomicAdd(fp + 6, sc * bf16lo(hv.w));
                        unsafeAtomicAdd(fp + 7, sc * bf16hi(hv.w));
                    }
                }
                __syncthreads();
                // A-frags straight from fAcc (fp32 -> bf16), MFMA
                #pragma unroll
                for (int kt = 0; kt < 4; ++kt) {
                    const float* ap = &fAcc[(mblk * 16 + lrow) * LDF + kt * 32 + quad * 8];
                    float4 f0 = *(const float4*)(ap);
                    float4 f1 = *(const float4*)(ap + 4);
                    short8 a = pack_bf16x8(f0, f1);
                    #pragma unroll
                    for (int nt = 0; nt < 2; ++nt) {
                        short8 bb = *(const short8*)(&sB[(nblk * 32 + nt * 16 + lrow) * LDB + kt * 32 + quad * 8]);
                        acc[nt] = __builtin_amdgcn_mfma_f32_16x16x32_bf16(a, bb, acc[nt], 0, 0, 0);
                    }
                }
            } else {
                __syncthreads();                // sB staged
                int node = nb + mblk * 16 + lrow;
                #pragma unroll
                for (int kt = 0; kt < 4; ++kt) {
                    short8 a;
                    if (node < N_NODES) a = *(const short8*)(h2 + (size_t)node * F + kt * 32 + quad * 8);
                    else a = (short8){0,0,0,0,0,0,0,0};
                    #pragma unroll
                    for (int nt = 0; nt < 2; ++nt) {
                        short8 bb = *(const short8*)(&sB[(nblk * 32 + nt * 16 + lrow) * LDB + kt * 32 + quad * 8]);
                        acc[nt] = __builtin_amdgcn_mfma_f32_16x16x32_bf16(a, bb, acc[nt], 0, 0, 0);
                    }
                }
            }
        }
        // epilogue: bias + relu
        #pragma unroll
        for (int nt = 0; nt < 2; ++nt) {
            int col = nblk * 32 + nt * 16 + lrow;
            float bv = bias[col];
            #pragma unroll
            for (int g = 0; g < 4; ++g) {
                int row = nb + mblk * 16 + quad * 4 + g;
                if (row < N_NODES)
                    out[(size_t)row * F + col] = fmaxf(acc[nt][g] + bv, 0.f);
            }
        }
    }
}

// ---------- ws-free safety fallback ----------
__global__ void k_edges_fb(const float* __restrict__ h, const float* __restrict__ W,
                           const float* __restrict__ gw, const float* __restrict__ norm,
                           const int* __restrict__ src, const int* __restrict__ dst,
                           const int* __restrict__ rel, float* __restrict__ out) {
    int wave = threadIdx.x >> 6, lane = threadIdx.x & 63;
    int e = blockIdx.x * 4 + wave;
    if (e >= N_EDGES) return;
    int s = src[e], d = dst[e], r = rel[e];
    float2 hv = *(const float2*)(h + (size_t)s * F + lane * 2);
    float2 gv = *(const float2*)(gw + r * F + lane * 2);
    float p = hv.x * gv.x + hv.y * gv.y;
    #pragma unroll
    for (int off = 32; off; off >>= 1) p += __shfl_xor(p, off);
    float scale = norm[e] * sigmoidf(p);
    const float* wr = W + ((size_t)r << 14);
    float a0 = 0.f, a1 = 0.f;
    for (int i2 = 0; i2 < 64; ++i2) {
        float x0 = __shfl(hv.x, i2), x1 = __shfl(hv.y, i2);
        a0 += x0 * wr[(2 * i2) * F + lane]      + x1 * wr[(2 * i2 + 1) * F + lane];
        a1 += x0 * wr[(2 * i2) * F + 64 + lane] + x1 * wr[(2 * i2 + 1) * F + 64 + lane];
    }
    unsafeAtomicAdd(out + (size_t)d * F + lane,      a0 * scale);
    unsafeAtomicAdd(out + (size_t)d * F + 64 + lane, a1 * scale);
}

__global__ void k_final_fb(const float* __restrict__ h, const float* __restrict__ LW,
                           const float* __restrict__ bias, float* __restrict__ out) {
    int wave = threadIdx.x >> 6, lane = threadIdx.x & 63;
    int n = blockIdx.x * 4 + wave;
    if (n >= N_NODES) return;
    float2 hv = *(const float2*)(h + (size_t)n * F + lane * 2);
    float a0 = 0.f, a1 = 0.f;
    for (int i2 = 0; i2 < 64; ++i2) {
        float x0 = __shfl(hv.x, i2), x1 = __shfl(hv.y, i2);
        a0 += x0 * LW[(2 * i2) * F + lane]      + x1 * LW[(2 * i2 + 1) * F + lane];
        a1 += x0 * LW[(2 * i2) * F + 64 + lane] + x1 * LW[(2 * i2 + 1) * F + 64 + lane];
    }
    float* op = out + (size_t)n * F;
    op[lane]      = fmaxf(op[lane]      + bias[lane]      + a0, 0.f);
    op[64 + lane] = fmaxf(op[64 + lane] + bias[64 + lane] + a1, 0.f);
}

extern "C" void kernel_launch(void* const* d_in, const int* in_sizes, int n_in,
                              void* d_out, int out_size, void* d_ws, size_t ws_size,
                              hipStream_t stream) {
    const float* h    = (const float*)d_in[0];
    const float* W    = (const float*)d_in[1];
    const float* gw   = (const float*)d_in[2];
    const float* bias = (const float*)d_in[3];
    const float* lw   = (const float*)d_in[4];
    const float* norm = (const float*)d_in[5];
    const int* src    = (const int*)d_in[6];
    const int* dst    = (const int*)d_in[7];
    const int* rel    = (const int*)d_in[8];
    float* out = (float*)d_out;

    int blocksPerCU = 0;
    hipOccupancyMaxActiveBlocksPerMultiprocessor(&blocksPerCU, k_mega, 1024, 0);
    int numCU = 0;
    hipDeviceGetAttribute(&numCU, hipDeviceAttributeMultiprocessorCount, 0);
    int grid = blocksPerCU * numCU;
    if (grid > MAXGRID) grid = MAXGRID;

    if (ws_size >= WS_NEED && grid >= 64) {
        unsigned short* Wt   = (unsigned short*)((char*)d_ws + WT_OFF);
        unsigned short* h2   = (unsigned short*)((char*)d_ws + H2_OFF);
        float*          gate = (float*)((char*)d_ws + GATE_OFF);
        int*            cnt  = (int*)((char*)d_ws + CNT_OFF);
        int*            base = (int*)((char*)d_ws + BASE_OFF);
        int*            cur  = (int*)((char*)d_ws + CUR_OFF);
        int2*           rec  = (int2*)((char*)d_ws + REC_OFF);

        void* args[] = {
            (void*)&h, (void*)&gw, (void*)&W, (void*)&lw, (void*)&norm,
            (void*)&src, (void*)&dst, (void*)&rel, (void*)&bias, (void*)&out,
            (void*)&h2, (void*)&gate, (void*)&Wt, (void*)&cnt,
            (void*)&base, (void*)&cur, (void*)&rec
        };
        hipLaunchCooperativeKernel((void*)k_mega, dim3(grid), dim3(1024),
                                   args, 0, stream);
    } else {
        hipMemsetAsync(d_out, 0, (size_t)out_size * sizeof(float), stream);
        k_edges_fb<<<150000, 256, 0, stream>>>(h, W, gw, norm, src, dst, rel, out);
        k_final_fb<<<12500, 256, 0, stream>>>(h, lw, bias, out);
    }
}

// Round 8
// 506.389 us; speedup vs baseline: 1.7879x; 1.7879x over previous
//
#include <hip/hip_runtime.h>
#include <hip/hip_cooperative_groups.h>

namespace cg = cooperative_groups;

#define N_NODES 50000
#define N_EDGES 600000
#define F 128
#define NBIN 400000      // rel*N_NODES + dst bins
#define NCH  1563        // 256-bin chunks covering NBIN
#define NTILES 782       // ceil(50000/64)
#define MAXGRID 512

// ---------- ws layout (16-aligned) ----------
#define WT_OFF   0                 // 294,912 B   bf16 W [r][o][i], r=8 is loop_weight
#define H2_OFF   294912            // 12,800,000  bf16 h
#define GATE_OFF 13094912          // 1,600,000   sigmoid gates [r][n]
#define CNT_OFF  14694912          // 1,600,512   histogram (drained by scatter)
#define EXCL_OFF 16295424          // 1,600,512   per-chunk exclusive partials
#define BSUM_OFF 17895936          // 6,400       chunk sums (exclusive-scanned)
#define REC_OFF  17902336          // 4,800,000   {src, scale} per edge, (rel,dst)-sorted
#define WS_NEED  ((size_t)22702336)

#define LDA 136   // padded short stride: 272B rows, 16B-aligned

typedef __attribute__((ext_vector_type(8))) short short8;
typedef __attribute__((ext_vector_type(4))) float floatx4;

__device__ inline unsigned short f32_to_bf16(float f) {
    unsigned u = __float_as_uint(f);
    unsigned r = u + 0x7fff + ((u >> 16) & 1);
    return (unsigned short)(r >> 16);
}
__device__ inline float bf16lo(unsigned m) { return __uint_as_float(m << 16); }
__device__ inline float bf16hi(unsigned m) { return __uint_as_float(m & 0xffff0000u); }
__device__ inline float sigmoidf(float x) { return 1.f / (1.f + __expf(-x)); }

// ================== single cooperative mega-kernel ==================
__global__ __launch_bounds__(1024, 8) void k_mega(
        const float* __restrict__ h,    const float* __restrict__ gw,
        const float* __restrict__ W,    const float* __restrict__ LW,
        const float* __restrict__ norm, const int* __restrict__ src,
        const int* __restrict__ dst,    const int* __restrict__ rel,
        const float* __restrict__ bias, float* __restrict__ out,
        unsigned short* __restrict__ h2, float* __restrict__ gate,
        unsigned short* __restrict__ Wt, int* __restrict__ cnt,
        int* __restrict__ excl, int* __restrict__ bsum, int2* __restrict__ rec) {
    cg::grid_group grid = cg::this_grid();
    __shared__ unsigned short sA[64 * LDA];    // 17,408 B
    __shared__ unsigned short sB[128 * LDA];   // 34,816 B
    __shared__ int wsum[16];

    int tid = threadIdx.x;
    int w = tid >> 6, lane = tid & 63;
    int gtid = blockIdx.x * 1024 + tid;
    int nthreads = gridDim.x << 10;
    int gwid = blockIdx.x * 16 + w;
    int nwaves = gridDim.x << 4;

    // ---- P0: zero histogram ----
    for (int i = gtid; i < NBIN; i += nthreads) cnt[i] = 0;
    grid.sync();

    // ---- P1: Wt prep, h->bf16 + gates, (rel,dst) histogram ----
    for (int i = gtid; i < 9 * 128 * 128; i += nthreads) {
        int r = i >> 14, rem = i & 16383, ii = rem >> 7, o = rem & 127;
        float v = (r < 8) ? W[(r << 14) + (ii << 7) + o] : LW[(ii << 7) + o];
        Wt[(r << 14) + (o << 7) + ii] = f32_to_bf16(v);
    }
    for (int n = gwid; n < N_NODES; n += nwaves) {
        float2 hv = *(const float2*)(h + (size_t)n * F + lane * 2);
        unsigned val = (unsigned)f32_to_bf16(hv.x) | ((unsigned)f32_to_bf16(hv.y) << 16);
        *(unsigned*)(h2 + (size_t)n * F + lane * 2) = val;
        #pragma unroll
        for (int r = 0; r < 8; ++r) {
            float2 wv = *(const float2*)(gw + r * F + lane * 2);
            float p = hv.x * wv.x + hv.y * wv.y;
            #pragma unroll
            for (int off = 32; off; off >>= 1) p += __shfl_xor(p, off);
            if (lane == 0) gate[r * N_NODES + n] = sigmoidf(p);
        }
    }
    for (int e = gtid; e < N_EDGES; e += nthreads)
        atomicAdd(&cnt[rel[e] * N_NODES + dst[e]], 1);
    grid.sync();

    // ---- P2a: per-256-bin-chunk exclusive partials (one wave per chunk) ----
    for (int ch = gwid; ch < NCH; ch += nwaves) {
        int b0 = ch * 256 + lane * 4;
        int v0 = (b0 + 0 < NBIN) ? cnt[b0 + 0] : 0;
        int v1 = (b0 + 1 < NBIN) ? cnt[b0 + 1] : 0;
        int v2 = (b0 + 2 < NBIN) ? cnt[b0 + 2] : 0;
        int v3 = (b0 + 3 < NBIN) ? cnt[b0 + 3] : 0;
        int s = v0 + v1 + v2 + v3;
        int x = s;
        #pragma unroll
        for (int off = 1; off < 64; off <<= 1) {
            int t = __shfl_up(x, off);
            if (lane >= off) x += t;
        }
        int e0 = x - s;   // exclusive at lane's 4-bin group
        if (b0 + 0 < NBIN) excl[b0 + 0] = e0;
        if (b0 + 1 < NBIN) excl[b0 + 1] = e0 + v0;
        if (b0 + 2 < NBIN) excl[b0 + 2] = e0 + v0 + v1;
        if (b0 + 3 < NBIN) excl[b0 + 3] = e0 + v0 + v1 + v2;
        if (lane == 63) bsum[ch] = x;
    }
    grid.sync();

    // ---- P2b: block 0 exclusive-scans the 1563 chunk sums ----
    if (blockIdx.x == 0) {
        int i0 = tid * 2, i1 = tid * 2 + 1;
        int v0 = (i0 < NCH) ? bsum[i0] : 0;
        int v1 = (i1 < NCH) ? bsum[i1] : 0;
        int s = v0 + v1;
        int x = s;
        #pragma unroll
        for (int off = 1; off < 64; off <<= 1) {
            int t = __shfl_up(x, off);
            if (lane >= off) x += t;
        }
        if (lane == 63) wsum[w] = x;
        __syncthreads();
        if (w == 0) {
            int y = (lane < 16) ? wsum[lane] : 0;
            #pragma unroll
            for (int off = 1; off < 16; off <<= 1) {
                int t = __shfl_up(y, off);
                if (lane >= off) y += t;
            }
            if (lane < 16) wsum[lane] = y;
        }
        __syncthreads();
        int pre = (w > 0) ? wsum[w - 1] : 0;
        int run = pre + x - s;
        if (i0 < NCH) bsum[i0] = run;
        if (i1 < NCH) bsum[i1] = run + v0;
    }
    grid.sync();

    // ---- P3: scatter into (rel,dst)-sorted rec; drains cnt via atomicSub ----
    for (int e = gtid; e < N_EDGES; e += nthreads) {
        int d = dst[e], r = rel[e], s = src[e];
        int bin = r * N_NODES + d;
        int base = excl[bin] + bsum[bin >> 8];
        int old = atomicSub(&cnt[bin], 1);
        float sc = norm[e] * gate[r * N_NODES + s];
        rec[base + old - 1] = make_int2(s, __float_as_int(sc));
    }
    grid.sync();

    // ---- P4: fused per-64-node-tile aggregate->LDS + MFMA + epilogue (r5 body) ----
    int lrow = lane & 15, quad = lane >> 4;
    int mblk = w >> 2, nblk = w & 3;

    for (int tile = blockIdx.x; tile < NTILES; tile += gridDim.x) {
        int nb = tile * 64;
        int n0w = nb + w * 4;
        floatx4 acc[2];
        acc[0] = (floatx4){0.f, 0.f, 0.f, 0.f};
        acc[1] = (floatx4){0.f, 0.f, 0.f, 0.f};

        for (int kb = 0; kb < 9; ++kb) {
            __syncthreads();   // previous MFMA reads of sA/sB complete
            // stage W_kb
            #pragma unroll
            for (int it = 0; it < 2; ++it) {
                int G = it * 1024 + tid;
                int row = G >> 4, gr = G & 15;
                *(uint4*)(&sB[row * LDA + gr * 8]) = *(const uint4*)(Wt + (kb << 14) + G * 8);
            }
            if (kb < 8) {
                // segment bounds for this wave's 4 rows (+1)
                int b = 0;
                if (lane < 5) {
                    int node = n0w + lane;
                    int nd = (node < N_NODES) ? node : N_NODES;
                    int eff = kb * N_NODES + nd;
                    b = (eff < NBIN) ? (excl[eff] + bsum[eff >> 8]) : N_EDGES;
                }
                int b0 = __shfl(b, 0);
                int degT = __shfl(b, 4) - b0;
                int rs = 0, rscl = 0;
                if (lane < degT) {                  // batch-load up to 64 edge records
                    int2 rc = rec[b0 + lane];
                    rs = rc.x; rscl = rc.y;
                }
                #pragma unroll
                for (int rr = 0; rr < 4; ++rr) {
                    int s = __shfl(b, rr), e = __shfl(b, rr + 1);
                    float a0 = 0.f, a1 = 0.f;
                    for (int j = s; j < e; ++j) {
                        int off = j - b0;
                        int sj; float sc;
                        if (off < 64) {             // wave-uniform branch
                            sj = __shfl(rs, off);
                            sc = __int_as_float(__shfl(rscl, off));
                        } else {                    // rare overflow: uniform direct load
                            int2 rc = rec[j];
                            sj = rc.x; sc = __int_as_float(rc.y);
                        }
                        unsigned m = *(const unsigned*)(h2 + (size_t)sj * F + lane * 2);
                        a0 += sc * bf16lo(m);
                        a1 += sc * bf16hi(m);
                    }
                    int row = w * 4 + rr;
                    unsigned val = (unsigned)f32_to_bf16(a0) | ((unsigned)f32_to_bf16(a1) << 16);
                    ((unsigned*)sA)[row * (LDA / 2) + lane] = val;
                }
            } else {
                // kb=8 self-loop: stage h2 rows directly (1024 granules)
                int row = tid >> 4, gr = tid & 15;
                int node = nb + row;
                uint4 v;
                if (node < N_NODES) v = *(const uint4*)(h2 + (size_t)node * F + gr * 8);
                else { v.x = 0; v.y = 0; v.z = 0; v.w = 0; }
                *(uint4*)(&sA[row * LDA + gr * 8]) = v;
            }
            __syncthreads();
            #pragma unroll
            for (int kt = 0; kt < 4; ++kt) {
                short8 a = *(const short8*)(&sA[(mblk * 16 + lrow) * LDA + kt * 32 + quad * 8]);
                #pragma unroll
                for (int nt = 0; nt < 2; ++nt) {
                    short8 bb = *(const short8*)(&sB[(nblk * 32 + nt * 16 + lrow) * LDA + kt * 32 + quad * 8]);
                    acc[nt] = __builtin_amdgcn_mfma_f32_16x16x32_bf16(a, bb, acc[nt], 0, 0, 0);
                }
            }
        }
        // epilogue: bias + relu
        #pragma unroll
        for (int nt = 0; nt < 2; ++nt) {
            int col = nblk * 32 + nt * 16 + lrow;
            float bv = bias[col];
            #pragma unroll
            for (int g = 0; g < 4; ++g) {
                int row = nb + mblk * 16 + quad * 4 + g;
                if (row < N_NODES)
                    out[(size_t)row * F + col] = fmaxf(acc[nt][g] + bv, 0.f);
            }
        }
    }
}

// ---------- ws-free safety fallback ----------
__global__ void k_edges_fb(const float* __restrict__ h, const float* __restrict__ W,
                           const float* __restrict__ gw, const float* __restrict__ norm,
                           const int* __restrict__ src, const int* __restrict__ dst,
                           const int* __restrict__ rel, float* __restrict__ out) {
    int wave = threadIdx.x >> 6, lane = threadIdx.x & 63;
    int e = blockIdx.x * 4 + wave;
    if (e >= N_EDGES) return;
    int s = src[e], d = dst[e], r = rel[e];
    float2 hv = *(const float2*)(h + (size_t)s * F + lane * 2);
    float2 gv = *(const float2*)(gw + r * F + lane * 2);
    float p = hv.x * gv.x + hv.y * gv.y;
    #pragma unroll
    for (int off = 32; off; off >>= 1) p += __shfl_xor(p, off);
    float scale = norm[e] * sigmoidf(p);
    const float* wr = W + ((size_t)r << 14);
    float a0 = 0.f, a1 = 0.f;
    for (int i2 = 0; i2 < 64; ++i2) {
        float x0 = __shfl(hv.x, i2), x1 = __shfl(hv.y, i2);
        a0 += x0 * wr[(2 * i2) * F + lane]      + x1 * wr[(2 * i2 + 1) * F + lane];
        a1 += x0 * wr[(2 * i2) * F + 64 + lane] + x1 * wr[(2 * i2 + 1) * F + 64 + lane];
    }
    unsafeAtomicAdd(out + (size_t)d * F + lane,      a0 * scale);
    unsafeAtomicAdd(out + (size_t)d * F + 64 + lane, a1 * scale);
}

__global__ void k_final_fb(const float* __restrict__ h, const float* __restrict__ LW,
                           const float* __restrict__ bias, float* __restrict__ out) {
    int wave = threadIdx.x >> 6, lane = threadIdx.x & 63;
    int n = blockIdx.x * 4 + wave;
    if (n >= N_NODES) return;
    float2 hv = *(const float2*)(h + (size_t)n * F + lane * 2);
    float a0 = 0.f, a1 = 0.f;
    for (int i2 = 0; i2 < 64; ++i2) {
        float x0 = __shfl(hv.x, i2), x1 = __shfl(hv.y, i2);
        a0 += x0 * LW[(2 * i2) * F + lane]      + x1 * LW[(2 * i2 + 1) * F + lane];
        a1 += x0 * LW[(2 * i2) * F + 64 + lane] + x1 * LW[(2 * i2 + 1) * F + 64 + lane];
    }
    float* op = out + (size_t)n * F;
    op[lane]      = fmaxf(op[lane]      + bias[lane]      + a0, 0.f);
    op[64 + lane] = fmaxf(op[64 + lane] + bias[64 + lane] + a1, 0.f);
}

extern "C" void kernel_launch(void* const* d_in, const int* in_sizes, int n_in,
                              void* d_out, int out_size, void* d_ws, size_t ws_size,
                              hipStream_t stream) {
    const float* h    = (const float*)d_in[0];
    const float* W    = (const float*)d_in[1];
    const float* gw   = (const float*)d_in[2];
    const float* bias = (const float*)d_in[3];
    const float* lw   = (const float*)d_in[4];
    const float* norm = (const float*)d_in[5];
    const int* src    = (const int*)d_in[6];
    const int* dst    = (const int*)d_in[7];
    const int* rel    = (const int*)d_in[8];
    float* out = (float*)d_out;

    int blocksPerCU = 0;
    hipOccupancyMaxActiveBlocksPerMultiprocessor(&blocksPerCU, k_mega, 1024, 0);
    int numCU = 0;
    hipDeviceGetAttribute(&numCU, hipDeviceAttributeMultiprocessorCount, 0);
    int grid = blocksPerCU * numCU;
    if (grid > MAXGRID) grid = MAXGRID;

    if (ws_size >= WS_NEED && grid >= 64) {
        unsigned short* Wt   = (unsigned short*)((char*)d_ws + WT_OFF);
        unsigned short* h2   = (unsigned short*)((char*)d_ws + H2_OFF);
        float*          gate = (float*)((char*)d_ws + GATE_OFF);
        int*            cnt  = (int*)((char*)d_ws + CNT_OFF);
        int*            excl = (int*)((char*)d_ws + EXCL_OFF);
        int*            bsum = (int*)((char*)d_ws + BSUM_OFF);
        int2*           rec  = (int2*)((char*)d_ws + REC_OFF);

        void* args[] = {
            (void*)&h, (void*)&gw, (void*)&W, (void*)&lw, (void*)&norm,
            (void*)&src, (void*)&dst, (void*)&rel, (void*)&bias, (void*)&out,
            (void*)&h2, (void*)&gate, (void*)&Wt, (void*)&cnt,
            (void*)&excl, (void*)&bsum, (void*)&rec
        };
        hipLaunchCooperativeKernel((void*)k_mega, dim3(grid), dim3(1024),
                                   args, 0, stream);
    } else {
        hipMemsetAsync(d_out, 0, (size_t)out_size * sizeof(float), stream);
        k_edges_fb<<<150000, 256, 0, stream>>>(h, W, gw, norm, src, dst, rel, out);
        k_final_fb<<<12500, 256, 0, stream>>>(h, lw, bias, out);
    }
}